// Round 4
// baseline (350.897 us; speedup 1.0000x reference)
//
#include <hip/hip_runtime.h>

// Problem: B=32, C=17, H=256, W=256 fp32.
// out = 0.5 * ( sum(m1?d:0)/sum(m1) + sum(m2?d:0)/(sum(m2)*C) )
//   m1 = target>0 per element; m2 = any(m1 over C) per (b,h,w); d = |input-target|.
//
// Strategy: all heavy traffic is FLAT CONTIGUOUS float4 streaming (the proven
// 6.3 TB/s copy pattern). The cross-channel OR (m2) is precomputed into a
// 256 KB per-(b,pixel) bitmask by a ballot-based pass over tgt.

typedef unsigned long long u64;
typedef unsigned int u32;

#define N_CH       17
#define QPP        16384               // float4-quads per (b,c) plane = HW/4
#define N_PLANES   (32 * N_CH)         // 544
#define N_QUADS    (N_PLANES * QPP)    // 8,912,896 flat float4s
#define GRID1      2048
#define ITERS      17                  // GRID1*256*ITERS == N_QUADS exactly
#define MASK_WORDS 32768               // 32 batches * 256 groups * 4 words
#define SLOT_OFF   (MASK_WORDS * 8)    // 256 KiB into d_ws

struct Slot { float s1, s2; u32 c1, c2; };

// Mask layout: group g = b*256 + (quad_in_plane >> 6) covers 256 consecutive
// pixels (64 quads). Word j (j=0..3) bit l = "any channel of pixel 4*l+j > 0".

__global__ __launch_bounds__(256) void mask_zero(u64* __restrict__ mask) {
    mask[blockIdx.x * 256 + threadIdx.x] = 0ULL;   // grid 128 -> 32768 words
}

// Pass A: flat contiguous sweep of tgt; build the pixel bitmask via ballots.
__global__ __launch_bounds__(256) void mask_build(const float* __restrict__ tgt,
                                                  u64* __restrict__ mask) {
    const float4* __restrict__ t4 = (const float4*)tgt;
    int f = blockIdx.x * 256 + threadIdx.x;
    const int lane = threadIdx.x & 63;
    #pragma unroll 1
    for (int it = 0; it < ITERS; ++it, f += GRID1 * 256) {
        float4 t = t4[f];
        u64 b0 = __ballot(t.x > 0.f);
        u64 b1 = __ballot(t.y > 0.f);
        u64 b2 = __ballot(t.z > 0.f);
        u64 b3 = __ballot(t.w > 0.f);
        int plane = f >> 14;                       // f / QPP
        int b = plane / N_CH;                      // magic-mul div
        int grp = b * 256 + ((f & (QPP - 1)) >> 6);
        if (lane < 4) {
            u64 w = (lane == 0) ? b0 : (lane == 1) ? b1 : (lane == 2) ? b2 : b3;
            if (w) atomicOr(&mask[(size_t)grp * 4 + lane], w);
        }
    }
}

// Pass B: flat contiguous sweep of inp+tgt; mask word per wave via uniform
// scalar load; per-block partials to private slots (no atomics).
__global__ __launch_bounds__(256) void heat_main(const float* __restrict__ inp,
                                                 const float* __restrict__ tgt,
                                                 const u64* __restrict__ mask,
                                                 Slot* __restrict__ slots) {
    const float4* __restrict__ t4 = (const float4*)tgt;
    const float4* __restrict__ x4 = (const float4*)inp;

    float s1 = 0.f, s2 = 0.f;
    u32 c1 = 0u, c2 = 0u;
    int f = blockIdx.x * 256 + threadIdx.x;
    const int lane = threadIdx.x & 63;

    #pragma unroll 1
    for (int it = 0; it < ITERS; ++it, f += GRID1 * 256) {
        float4 t = t4[f];
        float4 x = x4[f];

        int plane = f >> 14;
        int b = plane / N_CH;
        int grp = b * 256 + ((f & (QPP - 1)) >> 6);  // wave-uniform value
        u32 g = __builtin_amdgcn_readfirstlane((u32)grp);
        const u64* __restrict__ mw = mask + (size_t)g * 4;
        u64 w0 = mw[0], w1 = mw[1], w2 = mw[2], w3 = mw[3];

        float d0 = fabsf(x.x - t.x);
        float d1 = fabsf(x.y - t.y);
        float d2 = fabsf(x.z - t.z);
        float d3 = fabsf(x.w - t.w);

        bool p0 = t.x > 0.f, p1 = t.y > 0.f, p2 = t.z > 0.f, p3 = t.w > 0.f;
        s1 += p0 ? d0 : 0.f;  c1 += p0 ? 1u : 0u;
        s1 += p1 ? d1 : 0.f;  c1 += p1 ? 1u : 0u;
        s1 += p2 ? d2 : 0.f;  c1 += p2 ? 1u : 0u;
        s1 += p3 ? d3 : 0.f;  c1 += p3 ? 1u : 0u;

        u32 m0 = (u32)((w0 >> lane) & 1ULL);
        u32 m1 = (u32)((w1 >> lane) & 1ULL);
        u32 m2 = (u32)((w2 >> lane) & 1ULL);
        u32 m3 = (u32)((w3 >> lane) & 1ULL);
        s2 += m0 ? d0 : 0.f;  c2 += m0;
        s2 += m1 ? d1 : 0.f;  c2 += m1;
        s2 += m2 ? d2 : 0.f;  c2 += m2;
        s2 += m3 ? d3 : 0.f;  c2 += m3;
        // c2 counts elements (pixel-mask true, per channel) = sum(m2)*C.
    }

    // Intra-wave butterfly reduction (wave = 64 on gfx950)
    #pragma unroll
    for (int off = 32; off > 0; off >>= 1) {
        s1 += __shfl_down(s1, off);
        s2 += __shfl_down(s2, off);
        c1 += __shfl_down(c1, off);
        c2 += __shfl_down(c2, off);
    }
    __shared__ float ls1[4], ls2[4];
    __shared__ u32 lc1[4], lc2[4];
    const int wave = threadIdx.x >> 6;
    if (lane == 0) { ls1[wave] = s1; ls2[wave] = s2; lc1[wave] = c1; lc2[wave] = c2; }
    __syncthreads();
    if (threadIdx.x == 0) {
        Slot sl;
        sl.s1 = ls1[0] + ls1[1] + ls1[2] + ls1[3];
        sl.s2 = ls2[0] + ls2[1] + ls2[2] + ls2[3];
        sl.c1 = lc1[0] + lc1[1] + lc1[2] + lc1[3];
        sl.c2 = lc2[0] + lc2[1] + lc2[2] + lc2[3];
        slots[blockIdx.x] = sl;
    }
}

// Final: one block sums 2048 slots and writes the scalar.
__global__ __launch_bounds__(256) void final_reduce(const Slot* __restrict__ slots,
                                                    float* __restrict__ out) {
    float s1 = 0.f, s2 = 0.f;
    u32 c1 = 0u, c2 = 0u;
    for (int i = threadIdx.x; i < GRID1; i += 256) {
        Slot sl = slots[i];
        s1 += sl.s1; s2 += sl.s2; c1 += sl.c1; c2 += sl.c2;
    }
    #pragma unroll
    for (int off = 32; off > 0; off >>= 1) {
        s1 += __shfl_down(s1, off);
        s2 += __shfl_down(s2, off);
        c1 += __shfl_down(c1, off);
        c2 += __shfl_down(c2, off);
    }
    __shared__ float ls1[4], ls2[4];
    __shared__ u32 lc1[4], lc2[4];
    const int wave = threadIdx.x >> 6;
    const int lane = threadIdx.x & 63;
    if (lane == 0) { ls1[wave] = s1; ls2[wave] = s2; lc1[wave] = c1; lc2[wave] = c2; }
    __syncthreads();
    if (threadIdx.x == 0) {
        float S1 = ls1[0] + ls1[1] + ls1[2] + ls1[3];
        float S2 = ls2[0] + ls2[1] + ls2[2] + ls2[3];
        float C1 = (float)(lc1[0] + lc1[1] + lc1[2] + lc1[3]);
        float C2 = (float)(lc2[0] + lc2[1] + lc2[2] + lc2[3]);  // = sum(m2)*C
        float mean1 = S1 / C1;
        float mean2 = S2 / C2;
        out[0] = 0.5f * (mean1 + mean2);
    }
}

extern "C" void kernel_launch(void* const* d_in, const int* in_sizes, int n_in,
                              void* d_out, int out_size, void* d_ws, size_t ws_size,
                              hipStream_t stream) {
    const float* inp = (const float*)d_in[0];
    const float* tgt = (const float*)d_in[1];
    // d_in[2] (masks) and d_in[3] (hull) are unused by the forward pass.
    float* out = (float*)d_out;
    u64* mask = (u64*)d_ws;                          // 256 KiB
    Slot* slots = (Slot*)((char*)d_ws + SLOT_OFF);   // 32 KiB

    mask_zero<<<128, 256, 0, stream>>>(mask);
    mask_build<<<GRID1, 256, 0, stream>>>(tgt, mask);
    heat_main<<<GRID1, 256, 0, stream>>>(inp, tgt, mask, slots);
    final_reduce<<<1, 256, 0, stream>>>(slots, out);
}